// Round 4
// baseline (247.112 us; speedup 1.0000x reference)
//
#include <hip/hip_runtime.h>
#include <math.h>

#define WH 16384

typedef __attribute__((ext_vector_type(8))) short short8;   // 8 bf16 (4 VGPRs) MFMA frag
typedef __attribute__((ext_vector_type(4))) float f32x4;    // MFMA accumulator

__device__ __forceinline__ void atomAddF(float* p, float v) {
    __hip_atomic_fetch_add(p, v, __ATOMIC_RELAXED, __HIP_MEMORY_SCOPE_AGENT);
}
// fp32 -> bf16 round-to-nearest-even (integer trick)
__device__ __forceinline__ unsigned short f2bf(float x) {
    unsigned u = __float_as_uint(x);
    u += 0x7fff + ((u >> 16) & 1);
    return (unsigned short)(u >> 16);
}
__device__ __forceinline__ float bf2f(unsigned short h) {
    return __uint_as_float(((unsigned)h) << 16);
}

// ---------------- zero workspace (G + s regions; ws is poisoned 0xAA) --------
__global__ void zero_ws_kernel(float* __restrict__ p, int n) {
    int i = blockIdx.x * 256 + threadIdx.x;
    if (i < n) p[i] = 0.f;
}

// ---------------- pass A: G = X X^T via split-bf16 MFMA, + channel sums s ----
// R6: occupancy fix. R5 counters: all pipes <20%, occupancy 17.9% (2 blocks/CU
// capped by 64KB LDS) -> phase-serialized latency. Now: 128-px tiles -> 32KB
// LDS -> 4 blocks/CU (16 waves/CU), grid (32,16,2)=1024 blocks=4/CU exactly.
// Independent blocks at different phases cover each other's HBM latency.
// launch_bounds(256,4) caps VGPR at 128 so 16 waves/CU are schedulable.
// Same verified frag mapping + XOR slot swizzle, re-parameterized: row stride
// 128 ushorts, 16 slots of 8, XOR (row&15).
__global__ __launch_bounds__(256, 4) void gram_kernel(
    const float* __restrict__ xR, const float* __restrict__ xT,
    float* __restrict__ G, float* __restrict__ sv) {
    __shared__ unsigned short shi[8192];  // [64 ch][128 px] bf16 hi, 16 KB
    __shared__ unsigned short slo[8192];  // lo, 16 KB
    const int t = threadIdx.x, w = t >> 6, lane = t & 63;
    const int n = blockIdx.y, inp = blockIdx.z;
    const float* __restrict__ X = (inp ? xT : xR) + (size_t)n * 64 * WH;
    float* __restrict__ Gout = G + (size_t)(inp * 16 + n) * 4096;
    float* __restrict__ Sout = sv + (size_t)(inp * 16 + n) * 64;
    const int pbase = blockIdx.x << 9;  // 512 px per block, 4 tiles of 128

    f32x4 acc0 = {0.f, 0.f, 0.f, 0.f}, acc1 = acc0, acc2 = acc0, acc3 = acc0;
    float srow[8];
#pragma unroll
    for (int i = 0; i < 8; ++i) srow[i] = 0.f;

    const int m15 = lane & 15, q = lane >> 4;
    const int rowh = lane >> 5;           // which of 2 rows this half-wave loads
    const int l31 = lane & 31;
    const int s2 = l31 >> 1;              // slot 0..15
    const int qh = (lane & 1) << 2;       // ushort4 half within slot
    const int cha = (w << 4) + m15;
    const int ch0 = m15, ch1 = 16 + m15, ch2 = 32 + m15, ch3 = 48 + m15;

    // prologue: issue tile 0's 8 loads into the register buffer
    float4 vbuf[8];
#pragma unroll
    for (int i = 0; i < 8; ++i) {
        const int r = (i << 3) + (w << 1) + rowh;
        vbuf[i] = *(const float4*)(X + (size_t)r * WH + pbase + (l31 << 2));
    }

    for (int tile = 0; tile < 4; ++tile) {
        __syncthreads();  // previous tile's frag reads done
        // convert + swizzled LDS write from the reg buffer
#pragma unroll
        for (int i = 0; i < 8; ++i) {
            const int r = (i << 3) + (w << 1) + rowh;
            const float4 v = vbuf[i];
            srow[i] += v.x + v.y + v.z + v.w;
            const unsigned short h0 = f2bf(v.x), h1 = f2bf(v.y), h2 = f2bf(v.z), h3 = f2bf(v.w);
            const unsigned short l0 = f2bf(v.x - bf2f(h0)), l1 = f2bf(v.y - bf2f(h1)),
                                 l2 = f2bf(v.z - bf2f(h2)), l3 = f2bf(v.w - bf2f(h3));
            const int a = (r << 7) + ((s2 ^ (r & 15)) << 3) + qh;
            *(ushort4*)&shi[a] = make_ushort4(h0, h1, h2, h3);
            *(ushort4*)&slo[a] = make_ushort4(l0, l1, l2, l3);
        }
        __syncthreads();
        // issue NEXT tile's loads now -> in flight across the whole MFMA phase
        if (tile < 3) {
            const int p1 = pbase + ((tile + 1) << 7);
#pragma unroll
            for (int i = 0; i < 8; ++i) {
                const int r = (i << 3) + (w << 1) + rowh;
                vbuf[i] = *(const float4*)(X + (size_t)r * WH + p1 + (l31 << 2));
            }
        }
        // compute: wave w owns G row-block w; col-blocks 0..3
#pragma unroll
        for (int kk = 0; kk < 4; ++kk) {
            const int grp = (kk << 2) + q;
            const int offa = (cha << 7) + ((grp ^ (cha & 15)) << 3);
            const int off0 = (ch0 << 7) + ((grp ^ (ch0 & 15)) << 3);
            const int off1 = (ch1 << 7) + ((grp ^ (ch1 & 15)) << 3);
            const int off2 = (ch2 << 7) + ((grp ^ (ch2 & 15)) << 3);
            const int off3 = (ch3 << 7) + ((grp ^ (ch3 & 15)) << 3);
            const short8 ah = *(const short8*)&shi[offa];
            const short8 al = *(const short8*)&slo[offa];
            const short8 bh0 = *(const short8*)&shi[off0], bl0 = *(const short8*)&slo[off0];
            const short8 bh1 = *(const short8*)&shi[off1], bl1 = *(const short8*)&slo[off1];
            const short8 bh2 = *(const short8*)&shi[off2], bl2 = *(const short8*)&slo[off2];
            const short8 bh3 = *(const short8*)&shi[off3], bl3 = *(const short8*)&slo[off3];
            acc0 = __builtin_amdgcn_mfma_f32_16x16x32_bf16(ah, bh0, acc0, 0, 0, 0);
            acc0 = __builtin_amdgcn_mfma_f32_16x16x32_bf16(ah, bl0, acc0, 0, 0, 0);
            acc0 = __builtin_amdgcn_mfma_f32_16x16x32_bf16(al, bh0, acc0, 0, 0, 0);
            acc0 = __builtin_amdgcn_mfma_f32_16x16x32_bf16(al, bl0, acc0, 0, 0, 0);
            acc1 = __builtin_amdgcn_mfma_f32_16x16x32_bf16(ah, bh1, acc1, 0, 0, 0);
            acc1 = __builtin_amdgcn_mfma_f32_16x16x32_bf16(ah, bl1, acc1, 0, 0, 0);
            acc1 = __builtin_amdgcn_mfma_f32_16x16x32_bf16(al, bh1, acc1, 0, 0, 0);
            acc1 = __builtin_amdgcn_mfma_f32_16x16x32_bf16(al, bl1, acc1, 0, 0, 0);
            acc2 = __builtin_amdgcn_mfma_f32_16x16x32_bf16(ah, bh2, acc2, 0, 0, 0);
            acc2 = __builtin_amdgcn_mfma_f32_16x16x32_bf16(ah, bl2, acc2, 0, 0, 0);
            acc2 = __builtin_amdgcn_mfma_f32_16x16x32_bf16(al, bh2, acc2, 0, 0, 0);
            acc2 = __builtin_amdgcn_mfma_f32_16x16x32_bf16(al, bl2, acc2, 0, 0, 0);
            acc3 = __builtin_amdgcn_mfma_f32_16x16x32_bf16(ah, bh3, acc3, 0, 0, 0);
            acc3 = __builtin_amdgcn_mfma_f32_16x16x32_bf16(ah, bl3, acc3, 0, 0, 0);
            acc3 = __builtin_amdgcn_mfma_f32_16x16x32_bf16(al, bh3, acc3, 0, 0, 0);
            acc3 = __builtin_amdgcn_mfma_f32_16x16x32_bf16(al, bl3, acc3, 0, 0, 0);
        }
    }
    // epilogue: C/D map (verified m89/m91): col=lane&15, row=quad*4+reg
    const int rb = (w << 4) + (q << 2);
#pragma unroll
    for (int r = 0; r < 4; ++r) {
        atomAddF(&Gout[(rb + r) * 64 + 0 + m15], acc0[r]);
        atomAddF(&Gout[(rb + r) * 64 + 16 + m15], acc1[r]);
        atomAddF(&Gout[(rb + r) * 64 + 32 + m15], acc2[r]);
        atomAddF(&Gout[(rb + r) * 64 + 48 + m15], acc3[r]);
    }
    // channel sums: butterfly within each 32-lane half (two rows per wave-i)
#pragma unroll
    for (int i = 0; i < 8; ++i) {
        float v = srow[i];
        v += __shfl_xor(v, 16, 64);
        v += __shfl_xor(v, 8, 64);
        v += __shfl_xor(v, 4, 64);
        v += __shfl_xor(v, 2, 64);
        v += __shfl_xor(v, 1, 64);
        if (l31 == 0) atomAddF(&Sout[(i << 3) + (w << 1) + rowh], v);
    }
}

// ------- logits + softmax fused: rs = W G W^T + (Ws)b^T + b(Ws)^T + WH bb^T,
//         softmax over the 128 concatenated rows per column.
// R6: softmax reductions parallelized 4x (4 segments of 32 rows on all 256
// threads, combine in t<64) instead of 2x128 serial iters on 64 threads.
// att stored TRANSPOSED: attP[c][128 k] for outv's [row][k] fragments.
__global__ __launch_bounds__(256) void logits_softmax_kernel(
    const float* __restrict__ WR, const float* __restrict__ bR,
    const float* __restrict__ WT, const float* __restrict__ bT,
    const float* __restrict__ G, const float* __restrict__ sv,
    unsigned short* __restrict__ attb) {
    __shared__ float ldsW[4096];
    __shared__ float ldsWt[4096];
    __shared__ float ldsG[4096];
    __shared__ float ldsL[8192];  // logits [128][64]
    __shared__ float ldsS[64], ldsU[64], ldsMx[64], ldsInv[64];
    __shared__ float ldsP[256];   // 4-segment reduction scratch
    const int t = threadIdx.x, n = blockIdx.x;
    for (int inp = 0; inp < 2; ++inp) {
        const float* __restrict__ W = inp ? WT : WR;
        const float* __restrict__ b = inp ? bT : bR;
        const float* __restrict__ Gn = G + (size_t)(inp * 16 + n) * 4096;
        const float* __restrict__ sn = sv + (size_t)(inp * 16 + n) * 64;
        __syncthreads();  // protect LDS reuse across inp iterations
#pragma unroll
        for (int m = 0; m < 16; ++m) {
            const int idx = t + (m << 8);
            const float wv = W[idx];
            ldsW[idx] = wv;
            ldsWt[((idx & 63) << 6) + (idx >> 6)] = wv;
            ldsG[idx] = Gn[idx];
        }
        if (t < 64) ldsS[t] = sn[t];
        __syncthreads();
        if (t < 64) {
            float u = 0.f;
            for (int c = 0; c < 64; ++c) u += ldsW[(t << 6) + c] * ldsS[c];
            ldsU[t] = u;  // u = W s
        }
        const int d = t >> 2, e0 = (t & 3) << 4;
        float a[16];
#pragma unroll
        for (int e = 0; e < 16; ++e) a[e] = 0.f;
        for (int c = 0; c < 64; ++c) {
            const float wv = ldsW[(d << 6) + c];
#pragma unroll
            for (int e = 0; e < 16; ++e) a[e] += wv * ldsG[(c << 6) + e0 + e];
        }
        __syncthreads();
#pragma unroll
        for (int e = 0; e < 16; ++e) ldsG[(d << 6) + e0 + e] = a[e];  // M1 = W G
        __syncthreads();
        float r[16];
#pragma unroll
        for (int e = 0; e < 16; ++e) r[e] = 0.f;
        for (int c = 0; c < 64; ++c) {
            const float m1 = ldsG[(d << 6) + c];
#pragma unroll
            for (int e = 0; e < 16; ++e) r[e] += m1 * ldsWt[(c << 6) + e0 + e];
        }
        const float ud = ldsU[d], bd = b[d];
#pragma unroll
        for (int e = 0; e < 16; ++e) {
            const int ee = e0 + e;
            ldsL[((inp << 6) + d) * 64 + ee] =
                r[e] + ud * b[ee] + bd * ldsU[ee] + 16384.f * bd * b[ee];
        }
    }
    __syncthreads();
    // per-column max & sum over 128 rows, 4-way parallel segments
    const int c = t & 63, seg = t >> 6;
    {
        float mx = -1e30f;
        for (int k = (seg << 5); k < (seg << 5) + 32; ++k)
            mx = fmaxf(mx, ldsL[(k << 6) + c]);
        ldsP[(seg << 6) + c] = mx;
    }
    __syncthreads();
    if (t < 64)
        ldsMx[t] = fmaxf(fmaxf(ldsP[t], ldsP[64 + t]),
                         fmaxf(ldsP[128 + t], ldsP[192 + t]));
    __syncthreads();
    {
        float s = 0.f;
        for (int k = (seg << 5); k < (seg << 5) + 32; ++k)
            s += __expf(ldsL[(k << 6) + c] - ldsMx[c]);
        ldsP[(seg << 6) + c] = s;
    }
    __syncthreads();
    if (t < 64)
        ldsInv[t] = 1.f / (ldsP[t] + ldsP[64 + t] + ldsP[128 + t] + ldsP[192 + t]);
    __syncthreads();
    unsigned short* __restrict__ an = attb + (size_t)n * 8192;
#pragma unroll
    for (int i = 0; i < 32; ++i) {
        const int idx = (i << 8) + t;
        const int k = idx >> 6, cc = idx & 63;
        // transposed store: attP[c][k]
        an[(cc << 7) + k] = f2bf(__expf(ldsL[idx] - ldsMx[cc]) * ldsInv[cc]);
    }
}

// ---------------- pass B: out[n,c,p] = sum_k att[k][c] * [xR;xT][k][p] ------
// (unchanged from R5 — MFMA version; dropped out of top-5 at <67us)
__global__ __launch_bounds__(256, 2) void outv_kernel(
    const float* __restrict__ xR, const float* __restrict__ xT,
    const unsigned short* __restrict__ attb, float* __restrict__ out) {
    __shared__ unsigned short lxT[32768];  // [256 px][128 k] bf16, 64 KB
    __shared__ unsigned short lsa[8192];   // [64 c][128 k]  bf16, 16 KB
    const int t = threadIdx.x, w = t >> 6, lane = t & 63;
    const int m15 = lane & 15, q = lane >> 4;
    const int n = blockIdx.y;
    const int p0 = blockIdx.x << 8;
    const float* __restrict__ XR = xR + (size_t)n * 64 * WH + p0 + t;
    const float* __restrict__ XT = xT + (size_t)n * 64 * WH + p0 + t;
    const unsigned short* __restrict__ an = attb + (size_t)n * 8192;

    // --- stage attP -> lsa (swizzled) ---
#pragma unroll
    for (int i = 0; i < 8; ++i) {
        const int idx = (i << 10) + (t << 2);  // 4 ushorts: c = idx>>7, ke0 = idx&127
        const ushort4 av = *(const ushort4*)&an[idx];
        const int c = idx >> 7, ke0 = idx & 127;
        const int slot = ke0 >> 3;
        const int wb = (c << 7) + ((slot ^ (c & 15)) << 3) + (ke0 & 7);
        *(ushort4*)&lsa[wb] = av;
    }
    // --- stage X -> lxT (in-register transpose), 4 chunks of 32 k ---
    const int pxm = t & 15;
#pragma unroll
    for (int c4 = 0; c4 < 4; ++c4) {
        const float* __restrict__ base = (c4 < 2) ? XR : XT;
        float v[32];
#pragma unroll
        for (int j = 0; j < 32; ++j)
            v[j] = base[(size_t)((c4 & 1) * 32 + j) * WH];
#pragma unroll
        for (int s = 0; s < 4; ++s) {
            short8 pkt;
#pragma unroll
            for (int e = 0; e < 8; ++e) pkt[e] = (short)f2bf(v[(s << 3) + e]);
            const int slot = (c4 << 2) + s;
            *(short8*)&lxT[(t << 7) + ((slot ^ pxm) << 3)] = pkt;
        }
    }
    __syncthreads();

    // --- compute: wave w owns px tiles nt = 4w..4w+3, all 4 c tiles ---
    f32x4 z = {0.f, 0.f, 0.f, 0.f};
    f32x4 a00 = z, a01 = z, a02 = z, a03 = z;
    f32x4 a10 = z, a11 = z, a12 = z, a13 = z;
    f32x4 a20 = z, a21 = z, a22 = z, a23 = z;
    f32x4 a30 = z, a31 = z, a32 = z, a33 = z;
    const int rA0 = (0 * 16 + m15) << 7, rA1 = (1 * 16 + m15) << 7;
    const int rA2 = (2 * 16 + m15) << 7, rA3 = (3 * 16 + m15) << 7;
    const int rB0 = (((w << 2) + 0) * 16 + m15) << 7;
    const int rB1 = (((w << 2) + 1) * 16 + m15) << 7;
    const int rB2 = (((w << 2) + 2) * 16 + m15) << 7;
    const int rB3 = (((w << 2) + 3) * 16 + m15) << 7;
#pragma unroll
    for (int kg = 0; kg < 4; ++kg) {
        const int sx = (((kg << 2) + q) ^ m15) << 3;
        const short8 A0 = *(const short8*)&lsa[rA0 + sx];
        const short8 A1 = *(const short8*)&lsa[rA1 + sx];
        const short8 A2 = *(const short8*)&lsa[rA2 + sx];
        const short8 A3 = *(const short8*)&lsa[rA3 + sx];
        const short8 B0 = *(const short8*)&lxT[rB0 + sx];
        const short8 B1 = *(const short8*)&lxT[rB1 + sx];
        const short8 B2 = *(const short8*)&lxT[rB2 + sx];
        const short8 B3 = *(const short8*)&lxT[rB3 + sx];
        a00 = __builtin_amdgcn_mfma_f32_16x16x32_bf16(A0, B0, a00, 0, 0, 0);
        a01 = __builtin_amdgcn_mfma_f32_16x16x32_bf16(A0, B1, a01, 0, 0, 0);
        a02 = __builtin_amdgcn_mfma_f32_16x16x32_bf16(A0, B2, a02, 0, 0, 0);
        a03 = __builtin_amdgcn_mfma_f32_16x16x32_bf16(A0, B3, a03, 0, 0, 0);
        a10 = __builtin_amdgcn_mfma_f32_16x16x32_bf16(A1, B0, a10, 0, 0, 0);
        a11 = __builtin_amdgcn_mfma_f32_16x16x32_bf16(A1, B1, a11, 0, 0, 0);
        a12 = __builtin_amdgcn_mfma_f32_16x16x32_bf16(A1, B2, a12, 0, 0, 0);
        a13 = __builtin_amdgcn_mfma_f32_16x16x32_bf16(A1, B3, a13, 0, 0, 0);
        a20 = __builtin_amdgcn_mfma_f32_16x16x32_bf16(A2, B0, a20, 0, 0, 0);
        a21 = __builtin_amdgcn_mfma_f32_16x16x32_bf16(A2, B1, a21, 0, 0, 0);
        a22 = __builtin_amdgcn_mfma_f32_16x16x32_bf16(A2, B2, a22, 0, 0, 0);
        a23 = __builtin_amdgcn_mfma_f32_16x16x32_bf16(A2, B3, a23, 0, 0, 0);
        a30 = __builtin_amdgcn_mfma_f32_16x16x32_bf16(A3, B0, a30, 0, 0, 0);
        a31 = __builtin_amdgcn_mfma_f32_16x16x32_bf16(A3, B1, a31, 0, 0, 0);
        a32 = __builtin_amdgcn_mfma_f32_16x16x32_bf16(A3, B2, a32, 0, 0, 0);
        a33 = __builtin_amdgcn_mfma_f32_16x16x32_bf16(A3, B3, a33, 0, 0, 0);
    }
    // --- epilogue: C/D map col=lane&15 -> px, row=q*4+reg -> c ---
    float* __restrict__ on = out + (size_t)n * 64 * WH + p0;
#define ST(accv, mt, j)                                                          \
    {                                                                            \
        float* bp = on + (size_t)(((mt) << 4) + (q << 2)) * WH +                 \
                    (((w << 2) + (j)) << 4) + m15;                               \
        bp[0] = accv[0];                                                         \
        bp[WH] = accv[1];                                                        \
        bp[2 * WH] = accv[2];                                                    \
        bp[3 * WH] = accv[3];                                                    \
    }
    ST(a00, 0, 0); ST(a01, 0, 1); ST(a02, 0, 2); ST(a03, 0, 3);
    ST(a10, 1, 0); ST(a11, 1, 1); ST(a12, 1, 2); ST(a13, 1, 3);
    ST(a20, 2, 0); ST(a21, 2, 1); ST(a22, 2, 2); ST(a23, 2, 3);
    ST(a30, 3, 0); ST(a31, 3, 1); ST(a32, 3, 2); ST(a33, 3, 3);
#undef ST
}

extern "C" void kernel_launch(void* const* d_in, const int* in_sizes, int n_in,
                              void* d_out, int out_size, void* d_ws, size_t ws_size,
                              hipStream_t stream) {
    const float* xR = (const float*)d_in[0];
    const float* xT = (const float*)d_in[1];
    const float* WR = (const float*)d_in[2];
    const float* bR = (const float*)d_in[3];
    const float* WT = (const float*)d_in[4];
    const float* bT = (const float*)d_in[5];
    float* out = (float*)d_out;

    // ws: G [2][16][4096] f32 | s [2][16][64] f32 | attP bf16 [16][64][128]
    float* ws = (float*)d_ws;
    float* G = ws;
    float* sv = ws + 131072;
    unsigned short* attb = (unsigned short*)(ws + 133120);

    zero_ws_kernel<<<520, 256, 0, stream>>>(ws, 133120);
    gram_kernel<<<dim3(32, 16, 2), 256, 0, stream>>>(xR, xT, G, sv);
    logits_softmax_kernel<<<16, 256, 0, stream>>>(WR, bR, WT, bT, G, sv, attb);
    outv_kernel<<<dim3(64, 16), 256, 0, stream>>>(xR, xT, attb, out);
}